// Round 16
// baseline (318.330 us; speedup 1.0000x reference)
//
#include <hip/hip_runtime.h>
#include <hip/hip_fp16.h>
#include <math.h>

#define NN 100000
#define NE 3200000
#define IN_F 7
#define H 32

#define BSH 9                 // bucket shift: 512 nodes per bucket
#define BSPAN 512
#define NBUK ((NN + BSPAN - 1) / BSPAN)   // 196
#define EPB 8192              // edges per block in bucket passes

// ---------------- A0: bucket histogram ----------------
__global__ __launch_bounds__(1024) void k_bhist(const int* __restrict__ dst,
                                                int* __restrict__ bucket_cnt) {
    __shared__ int cnt[NBUK];
    for (int i = threadIdx.x; i < NBUK; i += 1024) cnt[i] = 0;
    __syncthreads();
    int base = blockIdx.x * EPB;
#pragma unroll
    for (int r = 0; r < EPB / 1024; ++r) {
        int e = base + r * 1024 + threadIdx.x;
        if (e < NE) atomicAdd(&cnt[dst[e] >> BSH], 1);
    }
    __syncthreads();
    for (int i = threadIdx.x; i < NBUK; i += 1024)
        if (cnt[i]) atomicAdd(&bucket_cnt[i], cnt[i]);
}

// ---------------- A1: scan bucket counts -> base + cursor ----------------
__global__ __launch_bounds__(256) void k_bscan(const int* __restrict__ bucket_cnt,
                                               int* __restrict__ bucket_base,
                                               int* __restrict__ bucket_cur) {
    __shared__ int tmp[256];
    int t = threadIdx.x;
    int v = (t < NBUK) ? bucket_cnt[t] : 0;
    tmp[t] = v;
    __syncthreads();
    for (int off = 1; off < 256; off <<= 1) {
        int u = (t >= off) ? tmp[t - off] : 0;
        __syncthreads();
        tmp[t] += u;
        __syncthreads();
    }
    int ex = tmp[t] - v;
    if (t < NBUK) {
        bucket_base[t] = ex;
        bucket_cur[t] = ex;
    }
    if (t == NBUK - 1) bucket_base[NBUK] = ex + v;  // == NE
}

// ---------------- A2: scatter packed pairs into bucket-contiguous storage --------
__global__ __launch_bounds__(1024) void k_bscatter(const int* __restrict__ src,
                                                   const int* __restrict__ dst,
                                                   int* __restrict__ bucket_cur,
                                                   unsigned int* __restrict__ pairs) {
    __shared__ int cnt[NBUK];
    __shared__ int cbase[NBUK];
    for (int i = threadIdx.x; i < NBUK; i += 1024) cnt[i] = 0;
    __syncthreads();
    int base = blockIdx.x * EPB;
#pragma unroll
    for (int r = 0; r < EPB / 1024; ++r) {
        int e = base + r * 1024 + threadIdx.x;
        if (e < NE) atomicAdd(&cnt[dst[e] >> BSH], 1);
    }
    __syncthreads();
    for (int i = threadIdx.x; i < NBUK; i += 1024) {
        int c = cnt[i];
        cbase[i] = c ? atomicAdd(&bucket_cur[i], c) : 0;
    }
    __syncthreads();
    for (int i = threadIdx.x; i < NBUK; i += 1024) cnt[i] = 0;
    __syncthreads();
#pragma unroll
    for (int r = 0; r < EPB / 1024; ++r) {
        int e = base + r * 1024 + threadIdx.x;
        if (e < NE) {
            int d = dst[e];
            int b = d >> BSH;
            int lp = atomicAdd(&cnt[b], 1);
            pairs[cbase[b] + lp] = ((unsigned int)src[e] << BSH) | (unsigned int)(d & (BSPAN - 1));
        }
    }
}

// ---------------- B: per-bucket deg/row_ptr/dinv + CSR fill (all LDS) ------------
__global__ __launch_bounds__(1024) void k_bfill(const unsigned int* __restrict__ pairs,
                                                const int* __restrict__ bucket_base,
                                                int* __restrict__ row_ptr,
                                                float* __restrict__ dinv,
                                                int* __restrict__ csr_src) {
    __shared__ int cnt[BSPAN];
    __shared__ int pre[BSPAN];
    int b = blockIdx.x;
    int ebeg = bucket_base[b], eend = bucket_base[b + 1];
    int t = threadIdx.x;
    for (int i = t; i < BSPAN; i += 1024) cnt[i] = 0;
    __syncthreads();
    for (int e = ebeg + t; e < eend; e += 1024)
        atomicAdd(&cnt[pairs[e] & (BSPAN - 1)], 1);
    __syncthreads();
    if (t < BSPAN) pre[t] = cnt[t];
    __syncthreads();
    for (int off = 1; off < BSPAN; off <<= 1) {
        int v = (t < BSPAN && t >= off) ? pre[t - off] : 0;
        __syncthreads();
        if (t < BSPAN) pre[t] += v;
        __syncthreads();
    }
    int nbase = b * BSPAN;
    if (t < BSPAN) {
        int node = nbase + t;
        if (node < NN) {
            row_ptr[node] = ebeg + pre[t] - cnt[t];
            dinv[node] = rsqrtf((float)cnt[t] + 1.0f);
        }
    }
    if (b == NBUK - 1 && t == 0) row_ptr[NN] = NE;
    __syncthreads();
    if (t < BSPAN) cnt[t] = ebeg + pre[t] - cnt[t];
    __syncthreads();
    for (int e = ebeg + t; e < eend; e += 1024) {
        unsigned int p = pairs[e];
        int pos = atomicAdd(&cnt[p & (BSPAN - 1)], 1);
        csr_src[pos] = (int)(p >> BSH);
    }
}

// ---------------- encoder (after dinv): hWd = dinv[n] * (relu(xW+b) @ Wgcn) -------
// Packed fp16, split into two 32 B column-slices (lo: cols 0-15, hi: 16-31).
__global__ __launch_bounds__(256) void k_encode(const float* __restrict__ x,
                                                const float* __restrict__ Wenc,
                                                const float* __restrict__ benc,
                                                const float* __restrict__ Wgcn,
                                                const float* __restrict__ dinv,
                                                uint4* __restrict__ lo,
                                                uint4* __restrict__ hi) {
    __shared__ float sWe[IN_F * H];
    __shared__ float sb[H];
    __shared__ float sWg[H * H];
    for (int i = threadIdx.x; i < IN_F * H; i += 256) sWe[i] = Wenc[i];
    for (int i = threadIdx.x; i < H; i += 256) sb[i] = benc[i];
    for (int i = threadIdx.x; i < H * H; i += 256) sWg[i] = Wgcn[i];
    __syncthreads();

    int n = blockIdx.x * 256 + threadIdx.x;
    if (n >= NN) return;

    float xl[IN_F];
#pragma unroll
    for (int j = 0; j < IN_F; ++j) xl[j] = x[n * IN_F + j];

    float h[H];
#pragma unroll
    for (int k = 0; k < H; ++k) {
        float a = sb[k];
#pragma unroll
        for (int j = 0; j < IN_F; ++j) a = fmaf(xl[j], sWe[j * H + k], a);
        h[k] = fmaxf(a, 0.f);
    }
    float dn = dinv[n];
    float a[H];
#pragma unroll
    for (int k = 0; k < H; ++k) {
        float s = 0.f;
#pragma unroll
        for (int j = 0; j < H; ++j) s = fmaf(h[j], sWg[j * H + k], s);
        a[k] = s * dn;
    }
    uint4 pk[2];
    __half2* hp = reinterpret_cast<__half2*>(pk);
#pragma unroll
    for (int k = 0; k < 8; ++k) hp[k] = __floats2half2_rn(a[2 * k], a[2 * k + 1]);
    lo[n * 2 + 0] = pk[0];
    lo[n * 2 + 1] = pk[1];
#pragma unroll
    for (int k = 0; k < 8; ++k) hp[k] = __floats2half2_rn(a[16 + 2 * k], a[16 + 2 * k + 1]);
    hi[n * 2 + 0] = pk[0];
    hi[n * 2 + 1] = pk[1];
}

// ---------------- gather pass over one 16-column slice (2 lanes/node) ------------
// tab slice = 3.2 MB -> fits each XCD's 4 MB L2. Writes partial scorer dots.
__global__ __launch_bounds__(256) void k_gather_p(const int* __restrict__ row_ptr,
                                                  const int* __restrict__ csr_src,
                                                  const float* __restrict__ dinv,
                                                  const uint4* __restrict__ tab,
                                                  const float* __restrict__ bg16,
                                                  const float* __restrict__ we_s,
                                                  const float* __restrict__ we_d,
                                                  float2* __restrict__ abp) {
    int tid = blockIdx.x * 256 + threadIdx.x;
    int n = tid >> 1;
    int c = tid & 1;          // lane owns halves [c*8, c*8+8) of this 16-col slice
    if (n >= NN) return;
    float dn = dinv[n];
    int beg = row_ptr[n], end = row_ptr[n + 1];
    float acc[8];
#pragma unroll
    for (int i = 0; i < 8; ++i) acc[i] = 0.f;
    for (int k = beg; k < end; ++k) {
        int s = csr_src[k];
        uint4 v = tab[s * 2 + c];
        const __half2* hp = reinterpret_cast<const __half2*>(&v);
#pragma unroll
        for (int i = 0; i < 4; ++i) {
            float2 f = __half22float2(hp[i]);
            acc[2 * i]     += f.x;
            acc[2 * i + 1] += f.y;
        }
    }
    uint4 w = tab[n * 2 + c];
    const __half2* wp = reinterpret_cast<const __half2*>(&w);
    float dota = 0.f, dotb = 0.f;
#pragma unroll
    for (int i = 0; i < 4; ++i) {
        float2 f = __half22float2(wp[i]);
        float r0 = fmaxf(fmaf(dn, acc[2 * i]     + f.x, bg16[c * 8 + 2 * i]),     0.f);
        float r1 = fmaxf(fmaf(dn, acc[2 * i + 1] + f.y, bg16[c * 8 + 2 * i + 1]), 0.f);
        dota = fmaf(r0, we_s[c * 8 + 2 * i],     dota);
        dota = fmaf(r1, we_s[c * 8 + 2 * i + 1], dota);
        dotb = fmaf(r0, we_d[c * 8 + 2 * i],     dotb);
        dotb = fmaf(r1, we_d[c * 8 + 2 * i + 1], dotb);
    }
    dota += __shfl_xor(dota, 1, 2);
    dotb += __shfl_xor(dotb, 1, 2);
    if (c == 0) abp[n] = make_float2(dota, dotb);
}

// ---------------- edge scorer = four 8B L2-resident lookups + sigmoid ------------
__global__ __launch_bounds__(256) void k_edge(const int* __restrict__ src,
                                              const int* __restrict__ dst,
                                              const float2* __restrict__ ab0,
                                              const float2* __restrict__ ab1,
                                              const float* __restrict__ be,
                                              float* __restrict__ out) {
    int e = blockIdx.x * 256 + threadIdx.x;
    if (e >= NE) return;
    int s = src[e];
    int d = dst[e];
    float logit = ab0[s].x + ab1[s].x + ab0[d].y + ab1[d].y + be[0];
    float sc = 1.0f / (1.0f + __expf(-logit));
    __builtin_nontemporal_store(sc, &out[e]);
}

extern "C" void kernel_launch(void* const* d_in, const int* in_sizes, int n_in,
                              void* d_out, int out_size, void* d_ws, size_t ws_size,
                              hipStream_t stream) {
    const float* x_t   = (const float*)d_in[0];
    // d_in[1] (x_t_dt) unused by the reference
    const int*   eidx  = (const int*)d_in[2];
    const float* Wenc  = (const float*)d_in[3];
    const float* benc  = (const float*)d_in[4];
    const float* Wgcn  = (const float*)d_in[5];
    const float* bgcn  = (const float*)d_in[6];
    const float* Wedge = (const float*)d_in[7];
    const float* bedge = (const float*)d_in[8];
    float* out = (float*)d_out;

    const int* src = eidx;
    const int* dst = eidx + NE;

    char* ws = (char*)d_ws;
    if (ws_size < 34500000) return;  // proven ws >= 39.2 MB in passing runs; can't happen

    // Layout (bytes):
    //   [0,        3.2M)   hWd_lo (fp16 cols 0-15, 32 B/node)
    //   [3.2M,     6.4M)   hWd_hi (fp16 cols 16-31)
    //   [6.4M,     19.2M)  pairs (uint32/edge)
    //   [19.2M,    32.0M)  csr_src
    //   [32.0M,    +400004) row_ptr
    //   [32.4M+64, +400000) dinv
    //   [32.8M+64, +800000) ab0
    //   [33.6M+64, +800000) ab1
    //   [34.4M+64 ..]       bucket_cnt / bucket_base / bucket_cur
    uint4*        lo       = (uint4*)(ws);
    uint4*        hi       = (uint4*)(ws + 3200000);
    unsigned int* pairs    = (unsigned int*)(ws + 6400000);
    int*          csr_src  = (int*)(ws + 19200000);
    int*          row_ptr  = (int*)(ws + 32000000);
    float*        dinv     = (float*)(ws + 32400064);
    float2*       ab0      = (float2*)(ws + 32800064);
    float2*       ab1      = (float2*)(ws + 33600064);
    int*          bucket_cnt  = (int*)(ws + 34400064);
    int*          bucket_base = (int*)(ws + 34401024);
    int*          bucket_cur  = (int*)(ws + 34402048);

    hipMemsetAsync(bucket_cnt, 0, NBUK * sizeof(int), stream);

    int ebks = (NE + EPB - 1) / EPB;  // 391
    k_bhist<<<ebks, 1024, 0, stream>>>(dst, bucket_cnt);
    k_bscan<<<1, 256, 0, stream>>>(bucket_cnt, bucket_base, bucket_cur);
    k_bscatter<<<ebks, 1024, 0, stream>>>(src, dst, bucket_cur, pairs);
    k_bfill<<<NBUK, 1024, 0, stream>>>(pairs, bucket_base, row_ptr, dinv, csr_src);
    k_encode<<<(NN + 255) / 256, 256, 0, stream>>>(x_t, Wenc, benc, Wgcn, dinv, lo, hi);
    k_gather_p<<<(NN * 2 + 255) / 256, 256, 0, stream>>>(row_ptr, csr_src, dinv, lo,
                                                         bgcn, Wedge, Wedge + H, ab0);
    k_gather_p<<<(NN * 2 + 255) / 256, 256, 0, stream>>>(row_ptr, csr_src, dinv, hi,
                                                         bgcn + 16, Wedge + 16, Wedge + H + 16, ab1);
    k_edge<<<(NE + 255) / 256, 256, 0, stream>>>(src, dst, ab0, ab1, bedge, out);
}